// Round 8
// baseline (124.060 us; speedup 1.0000x reference)
//
#include <hip/hip_runtime.h>

// Analytic collapse (verified R1-R6, absmax 9.8e-4):
//   <Z_0> = c1*...*c7,  <Z_j> = c0*...*cj,  c_j = cos(t_j + theta_j)
// R7: VALU-minimal rework of R6. 512 blocks x 256 thr; block = 16 tokens;
// ~71 KB LDS -> 2 blocks/CU. Inner loops are near-pure v_fma:
//  - W in LDS padded stride-130: ds_read_b64 @ 2*lane => bank-pair = lane%32
//    (2-way, free) and kk offset is an IMMEDIATE (520*kk B) => no addr VALU.
//  - x / scr broadcast via wave-uniform ds_read_b128 (1-bank, imm offsets)
//    => zero readlanes anywhere.
//  phase1 (all waves): 4 tokens/wave, 3 matrices; DPP prefix-product scans.
//  phase2 (waves 0,1): row-per-lane attention (R6-verified). waves 2,3
//    re-stage Wo into the dead Wq region concurrently.
//  phase3 (all waves): wo hoisted to 64 VGPR; scr rows broadcast-b128.

#define PS  130                 // dwords per kk-row of a transposed W matrix
#define WTM (32 * PS)           // 4160 dwords per matrix
#define SPS 66                  // sP token-row stride
#define SCS 68                  // sScr row stride (16B-aligned: 272 B)

// d *= dpp_row_shr<sh>(d) gated to lanes with (lane&7) >= sh
#define DPP_SHR_STEP(d, j, sh)                                                 \
    {                                                                          \
        float _t = __int_as_float(__builtin_amdgcn_update_dpp(                 \
            0x3f800000, __float_as_int(d), 0x110 + sh, 0xf, 0xf, false));      \
        d *= ((j) >= (sh)) ? _t : 1.0f;                                        \
    }

__global__ __launch_bounds__(256, 2)
void qattn_fused(const float* __restrict__ xg,
                 const float* __restrict__ wqg, const float* __restrict__ wkg,
                 const float* __restrict__ wvg, const float* __restrict__ wog,
                 const float* __restrict__ thg,
                 float* __restrict__ outg)
{
    __shared__ float sWt[3 * WTM];        // 48.75 KB  Wq,Wk,Wv (Wo re-staged over Wq)
    __shared__ __align__(16) float sX[16 * 64];   // 4 KB   x rows (broadcast-read)
    __shared__ float sP[48 * SPS];        // 12.4 KB  z values [(tt>>2)*3+m][tt&3][e]
    __shared__ __align__(16) float sScr[16 * SCS];// 4.25 KB scrambled rows [rho][col]

    const int tid  = threadIdx.x;
    const int lane = tid & 63;
    const int wg   = tid >> 6;
    const int j    = lane & 7;
    const int b    = blockIdx.x >> 5;
    const int grp  = blockIdx.x & 31;     // 16-token group in batch row

    // ---- stage Wq,Wk,Wv transposed: sWt[m][kk][2e+(k&1)], stride PS ----
    {
        const float* gm[3] = {wqg, wkg, wvg};
        #pragma unroll
        for (int m = 0; m < 3; ++m) {
            #pragma unroll
            for (int r = 0; r < 4; ++r) {
                const int g = tid + 256 * r;            // float4 idx 0..1023
                const float4 v = ((const float4*)gm[m])[g];
                const int e = g >> 4, kq = g & 15;      // k = 4kq..4kq+3
                *(float2*)&sWt[m * WTM + (2 * kq) * PS + 2 * e]     = make_float2(v.x, v.y);
                *(float2*)&sWt[m * WTM + (2 * kq + 1) * PS + 2 * e] = make_float2(v.z, v.w);
            }
        }
    }
    // ---- stage x: 16 tokens x 64 floats, coalesced b128 ----
    {
        const float4 xv = ((const float4*)(xg + (size_t)(b * 512 + grp * 16) * 64))[tid];
        *(float4*)&sX[tid * 4] = xv;
    }
    const float thf = thg[j];
    __syncthreads();

    // ---- phase 1: projections; lane = out elem e, 4 tokens per wave ----
    {
        float acc[3][4];
        #pragma unroll
        for (int m = 0; m < 3; ++m)
            #pragma unroll
            for (int t = 0; t < 4; ++t) acc[m][t] = 0.f;

        const float* w0 = &sWt[0 * WTM + 2 * lane];
        const float* w1 = &sWt[1 * WTM + 2 * lane];
        const float* w2 = &sWt[2 * WTM + 2 * lane];
        const float* xb0 = &sX[(wg * 4) * 64];

        #pragma unroll
        for (int kk2 = 0; kk2 < 16; ++kk2) {    // k = 4*kk2 .. 4*kk2+3
            float4 xt[4];
            #pragma unroll
            for (int t = 0; t < 4; ++t)          // wave-uniform b128 broadcast
                xt[t] = *(const float4*)(xb0 + t * 64 + kk2 * 4);
            const float2 qA = *(const float2*)(w0 + (2 * kk2) * PS);
            const float2 qB = *(const float2*)(w0 + (2 * kk2 + 1) * PS);
            const float2 kA = *(const float2*)(w1 + (2 * kk2) * PS);
            const float2 kB = *(const float2*)(w1 + (2 * kk2 + 1) * PS);
            const float2 vA = *(const float2*)(w2 + (2 * kk2) * PS);
            const float2 vB = *(const float2*)(w2 + (2 * kk2 + 1) * PS);
            #pragma unroll
            for (int t = 0; t < 4; ++t) {
                acc[0][t] = fmaf(qA.x, xt[t].x, fmaf(qA.y, xt[t].y, acc[0][t]));
                acc[0][t] = fmaf(qB.x, xt[t].z, fmaf(qB.y, xt[t].w, acc[0][t]));
                acc[1][t] = fmaf(kA.x, xt[t].x, fmaf(kA.y, xt[t].y, acc[1][t]));
                acc[1][t] = fmaf(kB.x, xt[t].z, fmaf(kB.y, xt[t].w, acc[1][t]));
                acc[2][t] = fmaf(vA.x, xt[t].x, fmaf(vA.y, xt[t].y, acc[2][t]));
                acc[2][t] = fmaf(vB.x, xt[t].z, fmaf(vB.y, xt[t].w, acc[2][t]));
            }
        }
        // z via DPP scans (R6-verified); write sP[((wg*3+m)*4+t)][e]
        #pragma unroll
        for (int m = 0; m < 3; ++m) {
            #pragma unroll
            for (int t = 0; t < 4; ++t) {
                const float c = __cosf(acc[m][t] + thf);
                float d = c;                      // inclusive scan (c0..cj)
                DPP_SHR_STEP(d, j, 1)
                DPP_SHR_STEP(d, j, 2)
                DPP_SHR_STEP(d, j, 4)
                float ex = (j == 0) ? 1.0f : c;   // scan excluding c0
                DPP_SHR_STEP(ex, j, 1)
                DPP_SHR_STEP(ex, j, 2)
                DPP_SHR_STEP(ex, j, 4)
                const int base = ((wg * 3 + m) * 4 + t) * SPS + lane;
                if (j > 0)  sP[base]     = d;     // z_j = c0..cj
                if (j == 7) sP[base - 7] = ex;    // z_0 = c1..c7 into slot j=0
            }
        }
    }
    __syncthreads();

    // ---- phase 2 (waves 0,1): row-per-lane attention, 8 tokens per wave ----
    if (wg < 2) {
        const int tg = wg * 8 + (lane >> 3);     // block-local token 0..15
        const int i  = lane & 7;                 // head (score row)
        const int qb = (((tg >> 2) * 3 + 0) * 4 + (tg & 3)) * SPS;
        const int kb = qb + 4 * SPS;             // m=1
        const int vb = qb + 8 * SPS;             // m=2
        float q[8];
        #pragma unroll
        for (int c = 0; c < 4; ++c)
            *(float2*)&q[2 * c] = *(const float2*)&sP[qb + 8 * i + 2 * c];
        float p[8];
        float sum = 0.f;
        #pragma unroll
        for (int jj = 0; jj < 8; ++jj) {         // |s| <= 2.83 -> no max-sub
            float kv[8];
            #pragma unroll
            for (int c = 0; c < 4; ++c)
                *(float2*)&kv[2 * c] = *(const float2*)&sP[kb + 8 * jj + 2 * c];
            float s = q[0] * kv[0];
            #pragma unroll
            for (int w = 1; w < 8; ++w) s = fmaf(q[w], kv[w], s);
            p[jj] = __expf(s * 0.35355339059327373f);
            sum += p[jj];
        }
        const float rinv = 1.0f / sum;
        float o[8];
        #pragma unroll
        for (int w = 0; w < 8; ++w) o[w] = 0.f;
        #pragma unroll
        for (int jj = 0; jj < 8; ++jj) {
            float vv[8];
            #pragma unroll
            for (int c = 0; c < 4; ++c)
                *(float2*)&vv[2 * c] = *(const float2*)&sP[vb + 8 * jj + 2 * c];
            const float a = p[jj] * rinv;
            #pragma unroll
            for (int w = 0; w < 8; ++w) o[w] = fmaf(a, vv[w], o[w]);
        }
        // scrambled row rho = i*2 + (tg>>3), col base 8*(tg&7); 2x b128
        float* sd = &sScr[(i * 2 + (tg >> 3)) * SCS + 8 * (tg & 7)];
        *(float4*)sd       = make_float4(o[0], o[1], o[2], o[3]);
        *(float4*)(sd + 4) = make_float4(o[4], o[5], o[6], o[7]);
    } else {
        // ---- waves 2,3: re-stage Wo into sWt[0..WTM) (Wq region, dead) ----
        const int lt = tid & 127;
        #pragma unroll
        for (int r = 0; r < 8; ++r) {
            const int g = lt + 128 * r;
            const float4 v = ((const float4*)wog)[g];
            const int e = g >> 4, kq = g & 15;
            *(float2*)&sWt[(2 * kq) * PS + 2 * e]     = make_float2(v.x, v.y);
            *(float2*)&sWt[(2 * kq + 1) * PS + 2 * e] = make_float2(v.z, v.w);
        }
    }
    __syncthreads();

    // ---- phase 3: y[r] = scr[rho] . Wo[e]; lane = e; 4 rows per wave ----
    {
        float wo[64];
        #pragma unroll
        for (int kk = 0; kk < 32; ++kk) {        // imm offsets, 2-way (free)
            const float2 w2v = *(const float2*)&sWt[kk * PS + 2 * lane];
            wo[2 * kk] = w2v.x; wo[2 * kk + 1] = w2v.y;
        }
        #pragma unroll
        for (int rr = 0; rr < 4; ++rr) {
            const int rho = wg * 4 + rr;
            float y0 = 0.f, y1 = 0.f, y2 = 0.f, y3 = 0.f;
            #pragma unroll
            for (int q4 = 0; q4 < 16; ++q4) {    // b128 broadcast of scr row
                const float4 sv = *(const float4*)&sScr[rho * SCS + q4 * 4];
                y0 = fmaf(wo[4 * q4],     sv.x, y0);
                y1 = fmaf(wo[4 * q4 + 1], sv.y, y1);
                y2 = fmaf(wo[4 * q4 + 2], sv.z, y2);
                y3 = fmaf(wo[4 * q4 + 3], sv.w, y3);
            }
            const float y = (y0 + y1) + (y2 + y3);
            const int head = rho >> 1, oct = rho & 1;
            outg[((size_t)(b * 512 + head * 64 + grp * 2 + oct)) * 64 + lane] = y;
        }
    }
}

extern "C" void kernel_launch(void* const* d_in, const int* in_sizes, int n_in,
                              void* d_out, int out_size, void* d_ws, size_t ws_size,
                              hipStream_t stream) {
    const float* x  = (const float*)d_in[0];
    const float* wq = (const float*)d_in[1];
    const float* wk = (const float*)d_in[2];
    const float* wv = (const float*)d_in[3];
    const float* wo = (const float*)d_in[4];
    const float* th = (const float*)d_in[5];
    float* out = (float*)d_out;
    // B=16, S=512: 16 batches x 32 sixteen-token groups = 512 blocks
    qattn_fused<<<dim3(512), dim3(256), 0, stream>>>(x, wq, wk, wv, wo, th, out);
}

// Round 9
// 123.022 us; speedup vs baseline: 1.0084x; 1.0084x over previous
//
#include <hip/hip_runtime.h>

// Analytic collapse (verified R1-R7, absmax 9.8e-4):
//   <Z_0> = c1*...*c7,  <Z_j> = c0*...*cj,  c_j = cos(t_j + theta_j)
// R8 = R7 minus the spill: NO per-thread arrays > 16 dwords anywhere.
// 512 blocks x 256 thr; block = 16 tokens; ~71 KB LDS -> 2 blocks/CU.
//  - W in LDS transposed, padded stride-130: ds_read_b64 @ 2*lane => 2-way
//    (free) and kk offset is an IMMEDIATE => no addr VALU in inner loops.
//  - x / scr rows broadcast via wave-uniform ds_read_b128 (1-bank, imm offs).
//  phase1 (all waves): 4 tokens/wave, 3 matrices; DPP prefix-product scans.
//  phase2 (waves 0,1): row-per-lane attention. waves 2,3 re-stage Wo into the
//    dead Wq region concurrently.
//  phase3 (all waves): STREAMED like phase 1 — y[4] accumulators, W and scr
//    read per k-quad from LDS (R7's wo[64] hoist spilled to scratch: 116 MB
//    HBM fetch at VGPR cap 128 — never again).

#define PS  130                 // dwords per kk-row of a transposed W matrix
#define WTM (32 * PS)           // 4160 dwords per matrix
#define SPS 66                  // sP token-row stride
#define SCS 68                  // sScr row stride (16B-aligned: 272 B)

// d *= dpp_row_shr<sh>(d) gated to lanes with (lane&7) >= sh
#define DPP_SHR_STEP(d, j, sh)                                                 \
    {                                                                          \
        float _t = __int_as_float(__builtin_amdgcn_update_dpp(                 \
            0x3f800000, __float_as_int(d), 0x110 + sh, 0xf, 0xf, false));      \
        d *= ((j) >= (sh)) ? _t : 1.0f;                                        \
    }

__global__ __launch_bounds__(256, 2)
void qattn_fused(const float* __restrict__ xg,
                 const float* __restrict__ wqg, const float* __restrict__ wkg,
                 const float* __restrict__ wvg, const float* __restrict__ wog,
                 const float* __restrict__ thg,
                 float* __restrict__ outg)
{
    __shared__ float sWt[3 * WTM];                 // 48.75 KB Wq,Wk,Wv (Wo overlays Wq)
    __shared__ __align__(16) float sX[16 * 64];    // 4 KB    x rows (broadcast-read)
    __shared__ float sP[48 * SPS];                 // 12.4 KB z values
    __shared__ __align__(16) float sScr[16 * SCS]; // 4.25 KB scrambled rows [rho][col]

    const int tid  = threadIdx.x;
    const int lane = tid & 63;
    const int wg   = tid >> 6;
    const int j    = lane & 7;
    const int b    = blockIdx.x >> 5;
    const int grp  = blockIdx.x & 31;     // 16-token group in batch row

    // ---- stage Wq,Wk,Wv transposed: sWt[m][kk][2e+(k&1)], stride PS ----
    {
        const float* gm[3] = {wqg, wkg, wvg};
        #pragma unroll
        for (int m = 0; m < 3; ++m) {
            #pragma unroll
            for (int r = 0; r < 4; ++r) {
                const int g = tid + 256 * r;            // float4 idx 0..1023
                const float4 v = ((const float4*)gm[m])[g];
                const int e = g >> 4, kq = g & 15;      // k = 4kq..4kq+3
                *(float2*)&sWt[m * WTM + (2 * kq) * PS + 2 * e]     = make_float2(v.x, v.y);
                *(float2*)&sWt[m * WTM + (2 * kq + 1) * PS + 2 * e] = make_float2(v.z, v.w);
            }
        }
    }
    // ---- stage x: 16 tokens x 64 floats, coalesced b128 ----
    {
        const float4 xv = ((const float4*)(xg + (size_t)(b * 512 + grp * 16) * 64))[tid];
        *(float4*)&sX[tid * 4] = xv;
    }
    const float thf = thg[j];
    __syncthreads();

    // ---- phase 1: projections; lane = out elem e, 4 tokens per wave ----
    {
        float acc[3][4];
        #pragma unroll
        for (int m = 0; m < 3; ++m)
            #pragma unroll
            for (int t = 0; t < 4; ++t) acc[m][t] = 0.f;

        const float* w0 = &sWt[0 * WTM + 2 * lane];
        const float* w1 = &sWt[1 * WTM + 2 * lane];
        const float* w2 = &sWt[2 * WTM + 2 * lane];
        const float* xb0 = &sX[(wg * 4) * 64];

        #pragma unroll
        for (int kk2 = 0; kk2 < 16; ++kk2) {    // k = 4*kk2 .. 4*kk2+3
            const float2 qA = *(const float2*)(w0 + (2 * kk2) * PS);
            const float2 qB = *(const float2*)(w0 + (2 * kk2 + 1) * PS);
            const float2 kA = *(const float2*)(w1 + (2 * kk2) * PS);
            const float2 kB = *(const float2*)(w1 + (2 * kk2 + 1) * PS);
            const float2 vA = *(const float2*)(w2 + (2 * kk2) * PS);
            const float2 vB = *(const float2*)(w2 + (2 * kk2 + 1) * PS);
            #pragma unroll
            for (int t = 0; t < 4; ++t) {        // load-and-consume: short live range
                const float4 xt = *(const float4*)(xb0 + t * 64 + kk2 * 4);
                acc[0][t] = fmaf(qA.x, xt.x, fmaf(qA.y, xt.y, acc[0][t]));
                acc[0][t] = fmaf(qB.x, xt.z, fmaf(qB.y, xt.w, acc[0][t]));
                acc[1][t] = fmaf(kA.x, xt.x, fmaf(kA.y, xt.y, acc[1][t]));
                acc[1][t] = fmaf(kB.x, xt.z, fmaf(kB.y, xt.w, acc[1][t]));
                acc[2][t] = fmaf(vA.x, xt.x, fmaf(vA.y, xt.y, acc[2][t]));
                acc[2][t] = fmaf(vB.x, xt.z, fmaf(vB.y, xt.w, acc[2][t]));
            }
        }
        // z via DPP scans (R6-verified); write sP[((wg*3+m)*4+t)][e]
        #pragma unroll
        for (int m = 0; m < 3; ++m) {
            #pragma unroll
            for (int t = 0; t < 4; ++t) {
                const float c = __cosf(acc[m][t] + thf);
                float d = c;                      // inclusive scan (c0..cj)
                DPP_SHR_STEP(d, j, 1)
                DPP_SHR_STEP(d, j, 2)
                DPP_SHR_STEP(d, j, 4)
                float ex = (j == 0) ? 1.0f : c;   // scan excluding c0
                DPP_SHR_STEP(ex, j, 1)
                DPP_SHR_STEP(ex, j, 2)
                DPP_SHR_STEP(ex, j, 4)
                const int base = ((wg * 3 + m) * 4 + t) * SPS + lane;
                if (j > 0)  sP[base]     = d;     // z_j = c0..cj
                if (j == 7) sP[base - 7] = ex;    // z_0 = c1..c7 into slot j=0
            }
        }
    }
    __syncthreads();

    // ---- phase 2 (waves 0,1): row-per-lane attention, 8 tokens per wave ----
    if (wg < 2) {
        const int tg = wg * 8 + (lane >> 3);     // block-local token 0..15
        const int i  = lane & 7;                 // head (score row)
        const int qb = (((tg >> 2) * 3 + 0) * 4 + (tg & 3)) * SPS;
        const int kb = qb + 4 * SPS;             // m=1
        const int vb = qb + 8 * SPS;             // m=2
        float q[8];
        #pragma unroll
        for (int c = 0; c < 4; ++c)
            *(float2*)&q[2 * c] = *(const float2*)&sP[qb + 8 * i + 2 * c];
        float p[8];
        float sum = 0.f;
        #pragma unroll
        for (int jj = 0; jj < 8; ++jj) {         // |s| <= 2.83 -> no max-sub
            float kv0, kv1;
            float s = 0.f;
            #pragma unroll
            for (int c = 0; c < 4; ++c) {
                const float2 kv = *(const float2*)&sP[kb + 8 * jj + 2 * c];
                s = fmaf(q[2 * c], kv.x, s);
                s = fmaf(q[2 * c + 1], kv.y, s);
            }
            p[jj] = __expf(s * 0.35355339059327373f);
            sum += p[jj];
        }
        const float rinv = 1.0f / sum;
        float o[8];
        #pragma unroll
        for (int w = 0; w < 8; ++w) o[w] = 0.f;
        #pragma unroll
        for (int jj = 0; jj < 8; ++jj) {
            const float a = p[jj] * rinv;
            #pragma unroll
            for (int c = 0; c < 4; ++c) {
                const float2 vv = *(const float2*)&sP[vb + 8 * jj + 2 * c];
                o[2 * c]     = fmaf(a, vv.x, o[2 * c]);
                o[2 * c + 1] = fmaf(a, vv.y, o[2 * c + 1]);
            }
        }
        // scrambled row rho = i*2 + (tg>>3), col base 8*(tg&7); 2x b128
        float* sd = &sScr[(i * 2 + (tg >> 3)) * SCS + 8 * (tg & 7)];
        *(float4*)sd       = make_float4(o[0], o[1], o[2], o[3]);
        *(float4*)(sd + 4) = make_float4(o[4], o[5], o[6], o[7]);
    } else {
        // ---- waves 2,3: re-stage Wo into sWt[0..WTM) (Wq region, dead) ----
        const int lt = tid & 127;
        #pragma unroll
        for (int r = 0; r < 8; ++r) {
            const int g = lt + 128 * r;
            const float4 v = ((const float4*)wog)[g];
            const int e = g >> 4, kq = g & 15;
            *(float2*)&sWt[(2 * kq) * PS + 2 * e]     = make_float2(v.x, v.y);
            *(float2*)&sWt[(2 * kq + 1) * PS + 2 * e] = make_float2(v.z, v.w);
        }
    }
    __syncthreads();

    // ---- phase 3: y[rho] = scr[rho] . Wo[e]; lane = e; 4 rows per wave.
    // STREAMED (no wo[] hoist): per k-quad 2 W-b64 (free) + 4 scr-b128 bcast.
    {
        const float* w0 = &sWt[2 * lane];
        float y0 = 0.f, y1 = 0.f, y2 = 0.f, y3 = 0.f;
        #pragma unroll
        for (int kk2 = 0; kk2 < 16; ++kk2) {
            const float2 wA = *(const float2*)(w0 + (2 * kk2) * PS);
            const float2 wB = *(const float2*)(w0 + (2 * kk2 + 1) * PS);
            const float4 s0 = *(const float4*)&sScr[(wg * 4 + 0) * SCS + kk2 * 4];
            const float4 s1 = *(const float4*)&sScr[(wg * 4 + 1) * SCS + kk2 * 4];
            const float4 s2 = *(const float4*)&sScr[(wg * 4 + 2) * SCS + kk2 * 4];
            const float4 s3 = *(const float4*)&sScr[(wg * 4 + 3) * SCS + kk2 * 4];
            y0 = fmaf(wA.x, s0.x, fmaf(wA.y, s0.y, y0));
            y0 = fmaf(wB.x, s0.z, fmaf(wB.y, s0.w, y0));
            y1 = fmaf(wA.x, s1.x, fmaf(wA.y, s1.y, y1));
            y1 = fmaf(wB.x, s1.z, fmaf(wB.y, s1.w, y1));
            y2 = fmaf(wA.x, s2.x, fmaf(wA.y, s2.y, y2));
            y2 = fmaf(wB.x, s2.z, fmaf(wB.y, s2.w, y2));
            y3 = fmaf(wA.x, s3.x, fmaf(wA.y, s3.y, y3));
            y3 = fmaf(wB.x, s3.z, fmaf(wB.y, s3.w, y3));
        }
        const size_t obase = (size_t)(b * 512) * 64 + lane;
        const int rho0 = wg * 4;
        // rho -> row: head = rho>>1, oct = rho&1; row = head*64 + grp*2 + oct
        outg[obase + ((size_t)((rho0 >> 1) * 64 + grp * 2 + (rho0 & 1))) * 64]       = y0;
        outg[obase + ((size_t)(((rho0 + 1) >> 1) * 64 + grp * 2 + ((rho0 + 1) & 1))) * 64] = y1;
        outg[obase + ((size_t)(((rho0 + 2) >> 1) * 64 + grp * 2 + ((rho0 + 2) & 1))) * 64] = y2;
        outg[obase + ((size_t)(((rho0 + 3) >> 1) * 64 + grp * 2 + ((rho0 + 3) & 1))) * 64] = y3;
    }
}

extern "C" void kernel_launch(void* const* d_in, const int* in_sizes, int n_in,
                              void* d_out, int out_size, void* d_ws, size_t ws_size,
                              hipStream_t stream) {
    const float* x  = (const float*)d_in[0];
    const float* wq = (const float*)d_in[1];
    const float* wk = (const float*)d_in[2];
    const float* wv = (const float*)d_in[3];
    const float* wo = (const float*)d_in[4];
    const float* th = (const float*)d_in[5];
    float* out = (float*)d_out;
    // B=16, S=512: 16 batches x 32 sixteen-token groups = 512 blocks
    qattn_fused<<<dim3(512), dim3(256), 0, stream>>>(x, wq, wk, wv, wo, th, out);
}

// Round 10
// 75.279 us; speedup vs baseline: 1.6480x; 1.6342x over previous
//
#include <hip/hip_runtime.h>

// Analytic collapse (verified R1-R8, absmax 9.8e-4):
//   <Z_0> = c1*...*c7,  <Z_j> = c0*...*cj,  c_j = cos(t_j + theta_j)
// R9 = R6 skeleton (the proven-fast one) with fewer barriers + no Wo staging.
// 512 blocks x 256 thr; block = 16 tokens; LDS 65 KB -> 2 blocks/CU.
//  stage Wq,Wk,Wv XOR-swizzled (R6-verified layout); x -> regs per lane.
//  P1 (all waves): own 4 tokens x 3 matrices; readlane-x + swizzled W reads
//    (the per-iter address VALU deliberately throttles the scheduler's load
//    hoisting — R7/R8's immediate-offset load avalanche spilled 226 MB to
//    scratch; do NOT "optimize" this addressing away).
//  P2 (all waves, NO barrier): wave-local attention on own 4 tokens
//    (lane = (t=lane>>4, i=lane&7); lanes with bit3 set duplicate, writes
//    gated). sP RAW within a wave is in-order DS (R2-verified).
//  P3 (all waves): Wo row hoisted per-lane from GLOBAL (L2-hot), scr row
//    broadcast via readlane (R6-verified pattern).

#define WT  4096   // dwords per XOR-swizzled W matrix (32 kk * 128)
#define SPS 68     // sP token-row stride (16B-aligned rows)
#define SCS 68     // sScr row stride

// d *= dpp_row_shr<sh>(d) gated to lanes with (lane&7) >= sh
#define DPP_SHR_STEP(d, j, sh)                                                 \
    {                                                                          \
        float _t = __int_as_float(__builtin_amdgcn_update_dpp(                 \
            0x3f800000, __float_as_int(d), 0x110 + sh, 0xf, 0xf, false));      \
        d *= ((j) >= (sh)) ? _t : 1.0f;                                        \
    }

__device__ __forceinline__ float rl(float v, int l) {
    return __int_as_float(__builtin_amdgcn_readlane(__float_as_int(v), l));
}

__global__ __launch_bounds__(256, 2)
void qattn_fused(const float* __restrict__ xg,
                 const float* __restrict__ wqg, const float* __restrict__ wkg,
                 const float* __restrict__ wvg, const float* __restrict__ wog,
                 const float* __restrict__ thg,
                 float* __restrict__ outg)
{
    __shared__ float sWt[3 * WT];             // 48 KB   Wq,Wk,Wv XOR-swizzled
    __shared__ __align__(16) float sP[48 * SPS];   // 12.75 KB z values
    __shared__ __align__(16) float sScr[16 * SCS]; // 4.25 KB scrambled rows

    const int tid  = threadIdx.x;
    const int lane = tid & 63;
    const int wg   = tid >> 6;
    const int j    = lane & 7;
    const int b    = blockIdx.x >> 5;
    const int grp  = blockIdx.x & 31;         // 16-token group in batch row

    // ---- stage Wq,Wk,Wv transposed + XOR-swizzled (R6 layout) ----
    {
        const float* gm[3] = {wqg, wkg, wvg};
        #pragma unroll
        for (int m = 0; m < 3; ++m) {
            #pragma unroll
            for (int r = 0; r < 4; ++r) {
                const int g = tid + 256 * r;            // float4 idx 0..1023
                const float4 v = ((const float4*)gm[m])[g];
                const int e = g >> 4, kq = g & 15;
                const int c0 = (2 * e + 4 * kq) & 127;
                const int c1 = (c0 + 2) & 127;
                *(float2*)&sWt[m * WT + 256 * kq + c0]       = make_float2(v.x, v.y);
                *(float2*)&sWt[m * WT + 256 * kq + 128 + c1] = make_float2(v.z, v.w);
            }
        }
    }
    // per-wave x rows (lane = column), own 4 tokens
    float xr[4];
    {
        const float* xb = xg + ((size_t)(b * 512 + grp * 16 + wg * 4)) * 64 + lane;
        xr[0] = xb[0]; xr[1] = xb[64]; xr[2] = xb[128]; xr[3] = xb[192];
    }
    const float thf = thg[j];
    __syncthreads();

    // ---- P1: projections (lane = out elem e) for this wave's 4 tokens ----
    {
        float acc[3][4];
        #pragma unroll
        for (int m = 0; m < 3; ++m)
            #pragma unroll
            for (int t = 0; t < 4; ++t) acc[m][t] = 0.f;

        #pragma unroll 8
        for (int kk = 0; kk < 32; ++kk) {
            const int col = (2 * lane + 2 * kk) & 127;
            const float2 wq = *(const float2*)&sWt[0 * WT + kk * 128 + col];
            const float2 wk = *(const float2*)&sWt[1 * WT + kk * 128 + col];
            const float2 wv = *(const float2*)&sWt[2 * WT + kk * 128 + col];
            #pragma unroll
            for (int t = 0; t < 4; ++t) {
                const float x0 = rl(xr[t], 2 * kk);
                const float x1 = rl(xr[t], 2 * kk + 1);
                acc[0][t] = fmaf(wq.x, x0, fmaf(wq.y, x1, acc[0][t]));
                acc[1][t] = fmaf(wk.x, x0, fmaf(wk.y, x1, acc[1][t]));
                acc[2][t] = fmaf(wv.x, x0, fmaf(wv.y, x1, acc[2][t]));
            }
        }
        // z via DPP scans; write sP[((wg*3+m)*4+t)][e]
        #pragma unroll
        for (int m = 0; m < 3; ++m) {
            #pragma unroll
            for (int t = 0; t < 4; ++t) {
                const float c = __cosf(acc[m][t] + thf);
                float d = c;                      // inclusive scan (c0..cj)
                DPP_SHR_STEP(d, j, 1)
                DPP_SHR_STEP(d, j, 2)
                DPP_SHR_STEP(d, j, 4)
                float ex = (j == 0) ? 1.0f : c;   // scan excluding c0
                DPP_SHR_STEP(ex, j, 1)
                DPP_SHR_STEP(ex, j, 2)
                DPP_SHR_STEP(ex, j, 4)
                const int base = ((wg * 3 + m) * 4 + t) * SPS + lane;
                if (j > 0)  sP[base]     = d;     // z_j = c0..cj
                if (j == 7) sP[base - 7] = ex;    // z_0 = c1..c7 into slot j=0
            }
        }
    }
    // NO barrier: P2 is wave-local (reads only this wave's sP rows; in-order DS)

    // ---- P2: wave-local attention; lane = (t = lane>>4, i = lane&7) ----
    {
        const int t  = lane >> 4;                 // 0..3 within wave
        const int i  = j;                         // head (score row)
        const int tt = wg * 4 + t;                // block-local token 0..15
        const int qb = ((wg * 3 + 0) * 4 + t) * SPS;
        const int kb = ((wg * 3 + 1) * 4 + t) * SPS;
        const int vb = ((wg * 3 + 2) * 4 + t) * SPS;
        float q[8];
        *(float4*)&q[0] = *(const float4*)&sP[qb + 8 * i];
        *(float4*)&q[4] = *(const float4*)&sP[qb + 8 * i + 4];
        float p[8];
        float sum = 0.f;
        #pragma unroll
        for (int jj = 0; jj < 8; ++jj) {          // |s| <= 2.83 -> no max-sub
            const float4 k0 = *(const float4*)&sP[kb + 8 * jj];
            const float4 k1 = *(const float4*)&sP[kb + 8 * jj + 4];
            float s = q[0] * k0.x;
            s = fmaf(q[1], k0.y, s); s = fmaf(q[2], k0.z, s);
            s = fmaf(q[3], k0.w, s); s = fmaf(q[4], k1.x, s);
            s = fmaf(q[5], k1.y, s); s = fmaf(q[6], k1.z, s);
            s = fmaf(q[7], k1.w, s);
            p[jj] = __expf(s * 0.35355339059327373f);
            sum += p[jj];
        }
        const float rinv = 1.0f / sum;
        float o[8];
        #pragma unroll
        for (int w = 0; w < 8; ++w) o[w] = 0.f;
        #pragma unroll
        for (int jj = 0; jj < 8; ++jj) {
            const float4 v0 = *(const float4*)&sP[vb + 8 * jj];
            const float4 v1 = *(const float4*)&sP[vb + 8 * jj + 4];
            const float a = p[jj] * rinv;
            o[0] = fmaf(a, v0.x, o[0]); o[1] = fmaf(a, v0.y, o[1]);
            o[2] = fmaf(a, v0.z, o[2]); o[3] = fmaf(a, v0.w, o[3]);
            o[4] = fmaf(a, v1.x, o[4]); o[5] = fmaf(a, v1.y, o[5]);
            o[6] = fmaf(a, v1.z, o[6]); o[7] = fmaf(a, v1.w, o[7]);
        }
        // scrambled row rho = i*2 + (tt>>3), col base 8*(tt&7)
        // lanes with bit3 set are duplicates -> gate the write
        if (!(lane & 8)) {
            float* sd = &sScr[(i * 2 + (tt >> 3)) * SCS + 8 * (tt & 7)];
            *(float4*)sd       = make_float4(o[0], o[1], o[2], o[3]);
            *(float4*)(sd + 4) = make_float4(o[4], o[5], o[6], o[7]);
        }
    }
    __syncthreads();

    // ---- P3: y[rho] = scr[rho] . Wo[e]; lane = e; Wo row from GLOBAL ----
    {
        float wo[64];
        #pragma unroll
        for (int kc = 0; kc < 16; ++kc) {         // per-lane row gather, L2-hot
            const float4 v = *(const float4*)(wog + lane * 64 + kc * 4);
            wo[4 * kc] = v.x; wo[4 * kc + 1] = v.y;
            wo[4 * kc + 2] = v.z; wo[4 * kc + 3] = v.w;
        }
        #pragma unroll
        for (int rr = 0; rr < 4; ++rr) {
            const int rho = wg * 4 + rr;
            const float sv = sScr[rho * SCS + lane];   // stride-1, conflict-free
            float y0 = 0.f, y1 = 0.f, y2 = 0.f, y3 = 0.f;
            #pragma unroll
            for (int k = 0; k < 64; k += 4) {
                y0 = fmaf(wo[k],     rl(sv, k),     y0);
                y1 = fmaf(wo[k + 1], rl(sv, k + 1), y1);
                y2 = fmaf(wo[k + 2], rl(sv, k + 2), y2);
                y3 = fmaf(wo[k + 3], rl(sv, k + 3), y3);
            }
            const float y = (y0 + y1) + (y2 + y3);
            const int head = rho >> 1, oct = rho & 1;
            outg[((size_t)(b * 512 + head * 64 + grp * 2 + oct)) * 64 + lane] = y;
        }
    }
}

extern "C" void kernel_launch(void* const* d_in, const int* in_sizes, int n_in,
                              void* d_out, int out_size, void* d_ws, size_t ws_size,
                              hipStream_t stream) {
    const float* x  = (const float*)d_in[0];
    const float* wq = (const float*)d_in[1];
    const float* wk = (const float*)d_in[2];
    const float* wv = (const float*)d_in[3];
    const float* wo = (const float*)d_in[4];
    const float* th = (const float*)d_in[5];
    float* out = (float*)d_out;
    // B=16, S=512: 16 batches x 32 sixteen-token groups = 512 blocks
    qattn_fused<<<dim3(512), dim3(256), 0, stream>>>(x, wq, wk, wv, wo, th, out);
}

// Round 11
// 73.278 us; speedup vs baseline: 1.6930x; 1.0273x over previous
//
#include <hip/hip_runtime.h>

// Analytic collapse (verified R1-R9, absmax 9.8e-4):
//   <Z_0> = c1*...*c7,  <Z_j> = c0*...*cj,  c_j = cos(t_j + theta_j)
// R10 = R9 skeleton + k-split for occupancy. 512 blocks x 512 thr (8 waves);
// block = 16 tokens; ~65 KB LDS -> 2 blocks/CU = 16 waves/CU = 4 waves/SIMD
// (vs R9's 2 — the diagnosed latency-exposure fix), at UNCHANGED total W-read
// DS traffic: wave pair (p, p+4) shares tokens 4p..4p+3, each wave does half
// of k. Even waves write raw partial dots; odd waves combine+cos+scan.
//  P1: R6-verified swizzled-W reads + readlane-x (per-iter addr VALU kept --
//      throttles the load hoister; R7/R8's imm-offset avalanche spilled 226MB).
//  B2..B3 window: odd waves finish z; waves 2,3 stage Wo into dead Wq region.
//  P2 (waves 0,1): R9's full-lane attention, 8 tokens/wave.
//  P3: 2 scrambled rows/wave; Wo row hoisted from LDS (stride 66, ~4-way b64);
//      scr broadcast via readlane (R6/R9-verified pattern).

#define WT  4096   // dwords per XOR-swizzled W matrix (32 kk * 128)
#define SPS 68     // sP row stride (16B-aligned rows)
#define SCS 68     // sScr row stride
#define WOS 66     // sWo row stride (overlaid on dead Wq/Wk region)

// d *= dpp_row_shr<sh>(d) gated to lanes with (lane&7) >= sh
#define DPP_SHR_STEP(d, j, sh)                                                 \
    {                                                                          \
        float _t = __int_as_float(__builtin_amdgcn_update_dpp(                 \
            0x3f800000, __float_as_int(d), 0x110 + sh, 0xf, 0xf, false));      \
        d *= ((j) >= (sh)) ? _t : 1.0f;                                        \
    }

__device__ __forceinline__ float rl(float v, int l) {
    return __int_as_float(__builtin_amdgcn_readlane(__float_as_int(v), l));
}

__global__ __launch_bounds__(512, 4)
void qattn_fused(const float* __restrict__ xg,
                 const float* __restrict__ wqg, const float* __restrict__ wkg,
                 const float* __restrict__ wvg, const float* __restrict__ wog,
                 const float* __restrict__ thg,
                 float* __restrict__ outg)
{
    __shared__ float sWt[3 * WT];                  // 48 KB  Wq,Wk,Wv swizzled
    __shared__ __align__(16) float sP[48 * SPS];   // 12.75 KB partials then z
    __shared__ __align__(16) float sScr[16 * SCS]; // 4.25 KB scrambled rows
    float* sWo = sWt;                              // overlays dead Wq/Wk in P3

    const int tid  = threadIdx.x;
    const int lane = tid & 63;
    const int wg   = tid >> 6;        // 0..7
    const int p    = wg & 3;          // token-quad pair id
    const int half = wg >> 2;         // k-half
    const int j    = lane & 7;
    const int b    = blockIdx.x >> 5;
    const int grp  = blockIdx.x & 31; // 16-token group in batch row

    // ---- stage Wq,Wk,Wv transposed + XOR-swizzled (R6 layout) ----
    {
        const float* gm[3] = {wqg, wkg, wvg};
        #pragma unroll
        for (int m = 0; m < 3; ++m) {
            #pragma unroll
            for (int r = 0; r < 2; ++r) {
                const int g = tid + 512 * r;            // float4 idx 0..1023
                const float4 v = ((const float4*)gm[m])[g];
                const int e = g >> 4, kq = g & 15;
                const int c0 = (2 * e + 4 * kq) & 127;
                const int c1 = (c0 + 2) & 127;
                *(float2*)&sWt[m * WT + 256 * kq + c0]       = make_float2(v.x, v.y);
                *(float2*)&sWt[m * WT + 256 * kq + 128 + c1] = make_float2(v.z, v.w);
            }
        }
    }
    // per-wave x rows (lane = column) for this pair's 4 tokens
    float xr[4];
    {
        const float* xb = xg + ((size_t)(b * 512 + grp * 16 + p * 4)) * 64 + lane;
        xr[0] = xb[0]; xr[1] = xb[64]; xr[2] = xb[128]; xr[3] = xb[192];
    }
    const float thf = thg[j];
    __syncthreads();                               // B1: sWt ready

    // ---- P1: half-k projections; lane = out elem e; 4 tokens ----
    float acc[3][4];
    #pragma unroll
    for (int m = 0; m < 3; ++m)
        #pragma unroll
        for (int t = 0; t < 4; ++t) acc[m][t] = 0.f;
    {
        const int kb0 = half * 16;
        #pragma unroll 8
        for (int kk = 0; kk < 16; ++kk) {
            const int kkg = kb0 + kk;
            const int col = (2 * lane + 2 * kkg) & 127;
            const float2 wq = *(const float2*)&sWt[0 * WT + kkg * 128 + col];
            const float2 wk = *(const float2*)&sWt[1 * WT + kkg * 128 + col];
            const float2 wv = *(const float2*)&sWt[2 * WT + kkg * 128 + col];
            #pragma unroll
            for (int t = 0; t < 4; ++t) {
                const float x0 = rl(xr[t], 2 * kkg);
                const float x1 = rl(xr[t], 2 * kkg + 1);
                acc[0][t] = fmaf(wq.x, x0, fmaf(wq.y, x1, acc[0][t]));
                acc[1][t] = fmaf(wk.x, x0, fmaf(wk.y, x1, acc[1][t]));
                acc[2][t] = fmaf(wv.x, x0, fmaf(wv.y, x1, acc[2][t]));
            }
        }
    }
    // even half writes raw partials (rows are this pair's canonical rows)
    if (half == 0) {
        #pragma unroll
        for (int m = 0; m < 3; ++m)
            #pragma unroll
            for (int t = 0; t < 4; ++t)
                sP[((p * 3 + m) * 4 + t) * SPS + lane] = acc[m][t];
    }
    __syncthreads();                               // B2: partials visible

    if (half == 1) {
        // ---- odd half: combine + cos + DPP prefix scans -> final z ----
        #pragma unroll
        for (int m = 0; m < 3; ++m) {
            #pragma unroll
            for (int t = 0; t < 4; ++t) {
                const int base = ((p * 3 + m) * 4 + t) * SPS + lane;
                const float ang = acc[m][t] + sP[base] + thf;
                const float c = __cosf(ang);
                float d = c;                       // inclusive scan (c0..cj)
                DPP_SHR_STEP(d, j, 1)
                DPP_SHR_STEP(d, j, 2)
                DPP_SHR_STEP(d, j, 4)
                float ex = (j == 0) ? 1.0f : c;    // scan excluding c0
                DPP_SHR_STEP(ex, j, 1)
                DPP_SHR_STEP(ex, j, 2)
                DPP_SHR_STEP(ex, j, 4)
                if (j > 0)  sP[base]     = d;      // z_j = c0..cj
                if (j == 7) sP[base - 7] = ex;     // z_0 = c1..c7 into slot 0
            }
        }
    } else if (wg >= 2) {
        // ---- waves 2,3: stage Wo (row-major, stride 66) over dead Wq/Wk ----
        const int lt = tid - 128;                  // 0..127
        #pragma unroll
        for (int r = 0; r < 8; ++r) {
            const int g = lt + 128 * r;            // float4 idx 0..1023
            const float4 v = ((const float4*)wog)[g];
            const int e = g >> 4, kq = g & 15;
            float* d = &sWo[e * WOS + 4 * kq];
            *(float2*)d       = make_float2(v.x, v.y);
            *(float2*)(d + 2) = make_float2(v.z, v.w);
        }
    }
    __syncthreads();                               // B3: z + sWo ready

    // ---- P2 (waves 0,1): full-lane attention; lane = (tg, i) ----
    if (wg < 2) {
        const int tg = wg * 8 + (lane >> 3);       // block-local token 0..15
        const int i  = j;                          // head (score row)
        const int p2 = tg >> 2, t2 = tg & 3;
        const int qb = ((p2 * 3 + 0) * 4 + t2) * SPS;
        const int kb = ((p2 * 3 + 1) * 4 + t2) * SPS;
        const int vb = ((p2 * 3 + 2) * 4 + t2) * SPS;
        float q[8];
        *(float4*)&q[0] = *(const float4*)&sP[qb + 8 * i];
        *(float4*)&q[4] = *(const float4*)&sP[qb + 8 * i + 4];
        float pr[8];
        float sum = 0.f;
        #pragma unroll
        for (int jj = 0; jj < 8; ++jj) {           // |s| <= 2.83 -> no max-sub
            const float4 k0 = *(const float4*)&sP[kb + 8 * jj];
            const float4 k1 = *(const float4*)&sP[kb + 8 * jj + 4];
            float s = q[0] * k0.x;
            s = fmaf(q[1], k0.y, s); s = fmaf(q[2], k0.z, s);
            s = fmaf(q[3], k0.w, s); s = fmaf(q[4], k1.x, s);
            s = fmaf(q[5], k1.y, s); s = fmaf(q[6], k1.z, s);
            s = fmaf(q[7], k1.w, s);
            pr[jj] = __expf(s * 0.35355339059327373f);
            sum += pr[jj];
        }
        const float rinv = 1.0f / sum;
        float o[8];
        #pragma unroll
        for (int w = 0; w < 8; ++w) o[w] = 0.f;
        #pragma unroll
        for (int jj = 0; jj < 8; ++jj) {
            const float4 v0 = *(const float4*)&sP[vb + 8 * jj];
            const float4 v1 = *(const float4*)&sP[vb + 8 * jj + 4];
            const float a = pr[jj] * rinv;
            o[0] = fmaf(a, v0.x, o[0]); o[1] = fmaf(a, v0.y, o[1]);
            o[2] = fmaf(a, v0.z, o[2]); o[3] = fmaf(a, v0.w, o[3]);
            o[4] = fmaf(a, v1.x, o[4]); o[5] = fmaf(a, v1.y, o[5]);
            o[6] = fmaf(a, v1.z, o[6]); o[7] = fmaf(a, v1.w, o[7]);
        }
        // scrambled row rho = i*2 + (tg>>3), col base 8*(tg&7)
        float* sd = &sScr[(i * 2 + (tg >> 3)) * SCS + 8 * (tg & 7)];
        *(float4*)sd       = make_float4(o[0], o[1], o[2], o[3]);
        *(float4*)(sd + 4) = make_float4(o[4], o[5], o[6], o[7]);
    }
    __syncthreads();                               // B4: sScr ready

    // ---- P3: y[rho] = scr[rho] . Wo[e]; lane = e; 2 rows per wave ----
    {
        float wo[64];
        #pragma unroll
        for (int c = 0; c < 32; ++c) {             // LDS row hoist, ~4-way b64
            const float2 v = *(const float2*)&sWo[lane * WOS + 2 * c];
            wo[2 * c] = v.x; wo[2 * c + 1] = v.y;
        }
        #pragma unroll
        for (int rr = 0; rr < 2; ++rr) {
            const int rho = wg * 2 + rr;
            const float sv = sScr[rho * SCS + lane];   // stride-1, conflict-free
            float y0 = 0.f, y1 = 0.f, y2 = 0.f, y3 = 0.f;
            #pragma unroll
            for (int k = 0; k < 64; k += 4) {
                y0 = fmaf(wo[k],     rl(sv, k),     y0);
                y1 = fmaf(wo[k + 1], rl(sv, k + 1), y1);
                y2 = fmaf(wo[k + 2], rl(sv, k + 2), y2);
                y3 = fmaf(wo[k + 3], rl(sv, k + 3), y3);
            }
            const float y = (y0 + y1) + (y2 + y3);
            const int head = rho >> 1, oct = rho & 1;
            outg[((size_t)(b * 512 + head * 64 + grp * 2 + oct)) * 64 + lane] = y;
        }
    }
}

extern "C" void kernel_launch(void* const* d_in, const int* in_sizes, int n_in,
                              void* d_out, int out_size, void* d_ws, size_t ws_size,
                              hipStream_t stream) {
    const float* x  = (const float*)d_in[0];
    const float* wq = (const float*)d_in[1];
    const float* wk = (const float*)d_in[2];
    const float* wv = (const float*)d_in[3];
    const float* wo = (const float*)d_in[4];
    const float* th = (const float*)d_in[5];
    float* out = (float*)d_out;
    // B=16, S=512: 16 batches x 32 sixteen-token groups = 512 blocks
    qattn_fused<<<dim3(512), dim3(512), 0, stream>>>(x, wq, wk, wv, wo, th, out);
}